// Round 2
// baseline (142.388 us; speedup 1.0000x reference)
//
#include <hip/hip_runtime.h>

#define NB 1024
#define BS 256
#define NWAVES (BS / 64)

// Per-point accumulation: gaussian-of-distance (un-normalized) + inside-triangle count.
// exp(-0.5*((d-2)/4)^2) == exp2(-(log2(e)/32) * (d-2)^2); exp2f -> single v_exp_f32.
// __builtin_amdgcn_sqrtf -> single v_sqrt_f32 (~1 ulp; output scale ~1e-6, ample headroom).
__device__ __forceinline__ void accum_point(
    float px, float py, float cx, float cy,
    float v0x, float v0y, float v1x, float v1y, float v2x, float v2y,
    float e0x, float e0y, float e1x, float e1y, float e2x, float e2y,
    float& sum_g, float& cnt) {
  const float dx = cx - px, dy = cy - py;
  const float r2 = fmaf(dx, dx, dy * dy);
  const float d = __builtin_amdgcn_sqrtf(r2);
  const float u = d - 2.0f;
  sum_g += exp2f(u * u * -0.045084220f);  // -0.5 * (1/16) * log2(e)
  const float c0 = e0x * (py - v0y) - e0y * (px - v0x);
  const float c1 = e1x * (py - v1y) - e1y * (px - v1x);
  const float c2 = e2x * (py - v2y) - e2y * (px - v2x);
  // strictly inside iff all crosses share a (nonzero) sign -> v_min3/v_max3 friendly
  const float mn = fminf(fminf(c0, c1), c2);
  const float mx = fmaxf(fmaxf(c0, c1), c2);
  cnt += (mn > 0.0f || mx < 0.0f) ? 1.0f : 0.0f;
}

// Single fused kernel: grid-stride reduce -> per-block partial slot (no float
// atomics) -> arrival counter -> last block reduces the NB partial pairs.
// ws layout: partials[0..NB-1]=sums, partials[NB..2NB-1]=counts, counter after.
__global__ __launch_bounds__(BS) void fused_kernel(
    const float* __restrict__ pts, const float* __restrict__ cam,
    float* __restrict__ partials, unsigned* __restrict__ counter,
    float* __restrict__ out, int n_points) {
  const float cx = cam[0], cy = cam[1], yaw = cam[2];
  const float c = cosf(yaw), s = sinf(yaw);
  // verts = POLY @ rot.T + pose[:2], POLY = (0,0),(2,7),(-2,7)
  const float v0x = cx,                     v0y = cy;
  const float v1x = 2.f * c - 7.f * s + cx, v1y = 2.f * s + 7.f * c + cy;
  const float v2x = -2.f * c - 7.f * s + cx, v2y = -2.f * s + 7.f * c + cy;
  const float e0x = v1x - v0x, e0y = v1y - v0y;
  const float e1x = v2x - v1x, e1y = v2y - v1y;
  const float e2x = v0x - v2x, e2y = v0y - v2y;

  float sum_g = 0.f, cnt = 0.f;

  const int tid = blockIdx.x * BS + threadIdx.x;
  const int stride = NB * BS;
  const int n4 = n_points >> 1;  // one float4 = 2 points
  const float4* __restrict__ p4 = (const float4*)pts;

  for (int i = tid; i < n4; i += stride) {
    float4 p = p4[i];
    accum_point(p.x, p.y, cx, cy, v0x, v0y, v1x, v1y, v2x, v2y,
                e0x, e0y, e1x, e1y, e2x, e2y, sum_g, cnt);
    accum_point(p.z, p.w, cx, cy, v0x, v0y, v1x, v1y, v2x, v2y,
                e0x, e0y, e1x, e1y, e2x, e2y, sum_g, cnt);
  }
  // odd-N tail (not hit for N=8M, kept for generality)
  if (tid == 0 && (n_points & 1)) {
    accum_point(pts[2 * (n_points - 1)], pts[2 * (n_points - 1) + 1],
                cx, cy, v0x, v0y, v1x, v1y, v2x, v2y,
                e0x, e0y, e1x, e1y, e2x, e2y, sum_g, cnt);
  }

  // wave (64-lane) shuffle reduction
  for (int off = 32; off > 0; off >>= 1) {
    sum_g += __shfl_down(sum_g, off, 64);
    cnt += __shfl_down(cnt, off, 64);
  }
  __shared__ float ls[NWAVES], lc[NWAVES];
  __shared__ int is_last;
  const int lane = threadIdx.x & 63, wid = threadIdx.x >> 6;
  if (lane == 0) { ls[wid] = sum_g; lc[wid] = cnt; }
  __syncthreads();
  if (threadIdx.x == 0) {
    float S = ls[0], C = lc[0];
    for (int w = 1; w < NWAVES; ++w) { S += ls[w]; C += lc[w]; }
    partials[blockIdx.x] = S;
    partials[NB + blockIdx.x] = C;
    __threadfence();  // release partials to agent scope
    const unsigned prev = __hip_atomic_fetch_add(
        counter, 1u, __ATOMIC_ACQ_REL, __HIP_MEMORY_SCOPE_AGENT);
    is_last = (prev == (unsigned)(NB - 1)) ? 1 : 0;
  }
  __syncthreads();

  if (is_last) {
    __threadfence();  // acquire: make all blocks' partials visible to this CU
    float S = 0.f, C = 0.f;
    for (int i = threadIdx.x; i < NB; i += BS) {
      S += partials[i];
      C += partials[NB + i];
    }
    for (int off = 32; off > 0; off >>= 1) {
      S += __shfl_down(S, off, 64);
      C += __shfl_down(C, off, 64);
    }
    __syncthreads();  // ls/lc reuse
    if (lane == 0) { ls[wid] = S; lc[wid] = C; }
    __syncthreads();
    if (threadIdx.x == 0) {
      float St = ls[0], Ct = lc[0];
      for (int w = 1; w < NWAVES; ++w) { St += ls[w]; Ct += lc[w]; }
      const float K = 0.09973557010f;  // 1/(4*sqrt(2*pi))
      const float eps = 1e-6f;
      out[0] = 1.0f / fmaf(St, K, eps) + 1.0f / (Ct + eps);
    }
  }
}

extern "C" void kernel_launch(void* const* d_in, const int* in_sizes, int n_in,
                              void* d_out, int out_size, void* d_ws, size_t ws_size,
                              hipStream_t stream) {
  const float* pts = (const float*)d_in[0];
  const float* cam = (const float*)d_in[1];
  float* out = (float*)d_out;
  float* partials = (float*)d_ws;                    // 2*NB floats = 8 KB
  unsigned* counter = (unsigned*)(partials + 2 * NB);
  const int n_points = in_sizes[0] / 2;

  // zero only the arrival counter (partials fully overwritten each run)
  hipMemsetAsync(counter, 0, sizeof(unsigned), stream);
  fused_kernel<<<NB, BS, 0, stream>>>(pts, cam, partials, counter, out, n_points);
}

// Round 3
// 95.019 us; speedup vs baseline: 1.4985x; 1.4985x over previous
//
#include <hip/hip_runtime.h>

#define NB 2048
#define BS 256
#define NWAVES (BS / 64)

// Per-point accumulation: gaussian-of-distance (un-normalized) + inside-triangle count.
// exp(-0.5*((d-2)/4)^2) == exp2(-(log2(e)/32) * (d-2)^2); exp2f -> single v_exp_f32.
// __builtin_amdgcn_sqrtf -> single v_sqrt_f32 (~1 ulp; output scale ~1e-6, ample headroom).
__device__ __forceinline__ void accum_point(
    float px, float py, float cx, float cy,
    float v0x, float v0y, float v1x, float v1y, float v2x, float v2y,
    float e0x, float e0y, float e1x, float e1y, float e2x, float e2y,
    float& sum_g, float& cnt) {
  const float dx = cx - px, dy = cy - py;
  const float r2 = fmaf(dx, dx, dy * dy);
  const float d = __builtin_amdgcn_sqrtf(r2);
  const float u = d - 2.0f;
  sum_g += exp2f(u * u * -0.045084220f);  // -0.5 * (1/16) * log2(e)
  const float c0 = e0x * (py - v0y) - e0y * (px - v0x);
  const float c1 = e1x * (py - v1y) - e1y * (px - v1x);
  const float c2 = e2x * (py - v2y) - e2y * (px - v2x);
  // strictly inside iff all crosses share a (nonzero) sign -> v_min3/v_max3
  const float mn = fminf(fminf(c0, c1), c2);
  const float mx = fmaxf(fmaxf(c0, c1), c2);
  cnt += (mn > 0.0f || mx < 0.0f) ? 1.0f : 0.0f;
}

// Kernel A: grid-stride, 4 independent float4 loads in flight per iteration
// (8 points), block-reduce, write per-block partials. No atomics, no fences —
// cross-XCD visibility comes from the inter-dispatch release/acquire.
__global__ __launch_bounds__(BS, 8) void reduce_kernel(
    const float* __restrict__ pts, const float* __restrict__ cam,
    float* __restrict__ partials, int n_points) {
  const float cx = cam[0], cy = cam[1], yaw = cam[2];
  // hardware sin/cos take revolutions; |yaw| small so no range reduction needed
  const float rev = yaw * 0.15915494309f;  // 1/(2*pi)
  const float c = __builtin_amdgcn_cosf(rev), s = __builtin_amdgcn_sinf(rev);
  // verts = POLY @ rot.T + pose[:2], POLY = (0,0),(2,7),(-2,7)
  const float v0x = cx,                     v0y = cy;
  const float v1x = 2.f * c - 7.f * s + cx, v1y = 2.f * s + 7.f * c + cy;
  const float v2x = -2.f * c - 7.f * s + cx, v2y = -2.f * s + 7.f * c + cy;
  const float e0x = v1x - v0x, e0y = v1y - v0y;
  const float e1x = v2x - v1x, e1y = v2y - v1y;
  const float e2x = v0x - v2x, e2y = v0y - v2y;

  float sum_g = 0.f, cnt = 0.f;

  const int tid = blockIdx.x * BS + threadIdx.x;
  const int stride = NB * BS;
  const int n4 = n_points >> 1;  // one float4 = 2 points
  const float4* __restrict__ p4 = (const float4*)pts;

  int i = tid;
  // main: 4 independent loads issued before any use -> 4x MLP per wave
  for (; i + 3 * stride < n4; i += 4 * stride) {
    const float4 a = p4[i];
    const float4 b = p4[i + stride];
    const float4 g = p4[i + 2 * stride];
    const float4 h = p4[i + 3 * stride];
    accum_point(a.x, a.y, cx, cy, v0x, v0y, v1x, v1y, v2x, v2y,
                e0x, e0y, e1x, e1y, e2x, e2y, sum_g, cnt);
    accum_point(a.z, a.w, cx, cy, v0x, v0y, v1x, v1y, v2x, v2y,
                e0x, e0y, e1x, e1y, e2x, e2y, sum_g, cnt);
    accum_point(b.x, b.y, cx, cy, v0x, v0y, v1x, v1y, v2x, v2y,
                e0x, e0y, e1x, e1y, e2x, e2y, sum_g, cnt);
    accum_point(b.z, b.w, cx, cy, v0x, v0y, v1x, v1y, v2x, v2y,
                e0x, e0y, e1x, e1y, e2x, e2y, sum_g, cnt);
    accum_point(g.x, g.y, cx, cy, v0x, v0y, v1x, v1y, v2x, v2y,
                e0x, e0y, e1x, e1y, e2x, e2y, sum_g, cnt);
    accum_point(g.z, g.w, cx, cy, v0x, v0y, v1x, v1y, v2x, v2y,
                e0x, e0y, e1x, e1y, e2x, e2y, sum_g, cnt);
    accum_point(h.x, h.y, cx, cy, v0x, v0y, v1x, v1y, v2x, v2y,
                e0x, e0y, e1x, e1y, e2x, e2y, sum_g, cnt);
    accum_point(h.z, h.w, cx, cy, v0x, v0y, v1x, v1y, v2x, v2y,
                e0x, e0y, e1x, e1y, e2x, e2y, sum_g, cnt);
  }
  // remainder
  for (; i < n4; i += stride) {
    const float4 p = p4[i];
    accum_point(p.x, p.y, cx, cy, v0x, v0y, v1x, v1y, v2x, v2y,
                e0x, e0y, e1x, e1y, e2x, e2y, sum_g, cnt);
    accum_point(p.z, p.w, cx, cy, v0x, v0y, v1x, v1y, v2x, v2y,
                e0x, e0y, e1x, e1y, e2x, e2y, sum_g, cnt);
  }
  // odd-N tail (not hit for N=8M, kept for generality)
  if (tid == 0 && (n_points & 1)) {
    accum_point(pts[2 * (n_points - 1)], pts[2 * (n_points - 1) + 1],
                cx, cy, v0x, v0y, v1x, v1y, v2x, v2y,
                e0x, e0y, e1x, e1y, e2x, e2y, sum_g, cnt);
  }

  // wave (64-lane) shuffle reduction
  for (int off = 32; off > 0; off >>= 1) {
    sum_g += __shfl_down(sum_g, off, 64);
    cnt += __shfl_down(cnt, off, 64);
  }
  __shared__ float ls[NWAVES], lc[NWAVES];
  const int lane = threadIdx.x & 63, wid = threadIdx.x >> 6;
  if (lane == 0) { ls[wid] = sum_g; lc[wid] = cnt; }
  __syncthreads();
  if (threadIdx.x == 0) {
    float S = ls[0], C = lc[0];
    for (int w = 1; w < NWAVES; ++w) { S += ls[w]; C += lc[w]; }
    partials[blockIdx.x] = S;
    partials[NB + blockIdx.x] = C;
  }
}

// Kernel B: one block reduces the NB partial pairs and writes the scalar output.
__global__ __launch_bounds__(BS) void finalize_kernel(
    const float* __restrict__ partials, float* __restrict__ out) {
  float S = 0.f, C = 0.f;
  for (int i = threadIdx.x; i < NB; i += BS) {
    S += partials[i];
    C += partials[NB + i];
  }
  for (int off = 32; off > 0; off >>= 1) {
    S += __shfl_down(S, off, 64);
    C += __shfl_down(C, off, 64);
  }
  __shared__ float ls[NWAVES], lc[NWAVES];
  const int lane = threadIdx.x & 63, wid = threadIdx.x >> 6;
  if (lane == 0) { ls[wid] = S; lc[wid] = C; }
  __syncthreads();
  if (threadIdx.x == 0) {
    float St = ls[0], Ct = lc[0];
    for (int w = 1; w < NWAVES; ++w) { St += ls[w]; Ct += lc[w]; }
    const float K = 0.09973557010f;  // 1/(4*sqrt(2*pi))
    const float eps = 1e-6f;
    out[0] = 1.0f / fmaf(St, K, eps) + 1.0f / (Ct + eps);
  }
}

extern "C" void kernel_launch(void* const* d_in, const int* in_sizes, int n_in,
                              void* d_out, int out_size, void* d_ws, size_t ws_size,
                              hipStream_t stream) {
  const float* pts = (const float*)d_in[0];
  const float* cam = (const float*)d_in[1];
  float* out = (float*)d_out;
  float* partials = (float*)d_ws;  // 2*NB floats = 16 KB
  const int n_points = in_sizes[0] / 2;

  reduce_kernel<<<NB, BS, 0, stream>>>(pts, cam, partials, n_points);
  finalize_kernel<<<1, BS, 0, stream>>>(partials, out);
}

// Round 4
// 93.757 us; speedup vs baseline: 1.5187x; 1.0135x over previous
//
#include <hip/hip_runtime.h>

#define NB 1024
#define BS 256
#define NWAVES (BS / 64)
#define UNROLL 8

// Per-point math: gaussian-of-distance (un-normalized) + inside-triangle test.
// exp(-0.5*((d-2)/4)^2) == exp2(-(log2(e)/32)*(d-2)^2); exp2f -> single v_exp_f32.
// __builtin_amdgcn_sqrtf -> single v_sqrt_f32 (~1 ulp; output scale ~1e-6).
__device__ __forceinline__ void accum_point(
    float px, float py, float w, float cx, float cy,
    float v0x, float v0y, float v1x, float v1y, float v2x, float v2y,
    float e0x, float e0y, float e1x, float e1y, float e2x, float e2y,
    float& sum_g, float& cnt) {
  const float dx = cx - px, dy = cy - py;
  const float r2 = fmaf(dx, dx, dy * dy);
  const float d = __builtin_amdgcn_sqrtf(r2);
  const float u = d - 2.0f;
  sum_g = fmaf(w, exp2f(u * u * -0.045084220f), sum_g);  // -0.5*(1/16)*log2(e)
  const float c0 = e0x * (py - v0y) - e0y * (px - v0x);
  const float c1 = e1x * (py - v1y) - e1y * (px - v1x);
  const float c2 = e2x * (py - v2y) - e2y * (px - v2x);
  // strictly inside iff all crosses share a (nonzero) sign -> v_min3/v_max3
  const float mn = fminf(fminf(c0, c1), c2);
  const float mx = fmaxf(fmaxf(c0, c1), c2);
  cnt += (mn > 0.0f || mx < 0.0f) ? w : 0.0f;
}

// Kernel A: grid-stride, 8 independent clamped float4 loads per iteration
// (16 points), contributions weighted by a validity flag -> no remainder loop,
// no divergence, 128 B outstanding per lane. Block-reduce to per-block partials.
__global__ __launch_bounds__(BS, 8) void reduce_kernel(
    const float* __restrict__ pts, const float* __restrict__ cam,
    float* __restrict__ partials, int n_points) {
  const float cx = cam[0], cy = cam[1], yaw = cam[2];
  // hardware sin/cos take revolutions; |yaw| small so no range reduction needed
  const float rev = yaw * 0.15915494309f;  // 1/(2*pi)
  const float c = __builtin_amdgcn_cosf(rev), s = __builtin_amdgcn_sinf(rev);
  // verts = POLY @ rot.T + pose[:2], POLY = (0,0),(2,7),(-2,7)
  const float v0x = cx,                     v0y = cy;
  const float v1x = 2.f * c - 7.f * s + cx, v1y = 2.f * s + 7.f * c + cy;
  const float v2x = -2.f * c - 7.f * s + cx, v2y = -2.f * s + 7.f * c + cy;
  const float e0x = v1x - v0x, e0y = v1y - v0y;
  const float e1x = v2x - v1x, e1y = v2y - v1y;
  const float e2x = v0x - v2x, e2y = v0y - v2y;

  float sum_g = 0.f, cnt = 0.f;

  const int tid = blockIdx.x * BS + threadIdx.x;
  const int stride = NB * BS;
  const int n4 = n_points >> 1;  // one float4 = 2 points
  const float4* __restrict__ p4 = (const float4*)pts;

  for (int i = tid; i < n4; i += UNROLL * stride) {
    float4 q[UNROLL];
    float w[UNROLL];
#pragma unroll
    for (int k = 0; k < UNROLL; ++k) {
      const int j = i + k * stride;
      const int jc = (j < n4) ? j : (n4 - 1);  // clamped: always legal, always issued
      q[k] = p4[jc];
      w[k] = (j < n4) ? 1.0f : 0.0f;
    }
#pragma unroll
    for (int k = 0; k < UNROLL; ++k) {
      accum_point(q[k].x, q[k].y, w[k], cx, cy, v0x, v0y, v1x, v1y, v2x, v2y,
                  e0x, e0y, e1x, e1y, e2x, e2y, sum_g, cnt);
      accum_point(q[k].z, q[k].w, w[k], cx, cy, v0x, v0y, v1x, v1y, v2x, v2y,
                  e0x, e0y, e1x, e1y, e2x, e2y, sum_g, cnt);
    }
  }
  // odd-N tail (not hit for N=8M, kept for generality)
  if (tid == 0 && (n_points & 1)) {
    accum_point(pts[2 * (n_points - 1)], pts[2 * (n_points - 1) + 1], 1.0f,
                cx, cy, v0x, v0y, v1x, v1y, v2x, v2y,
                e0x, e0y, e1x, e1y, e2x, e2y, sum_g, cnt);
  }

  // wave (64-lane) shuffle reduction
  for (int off = 32; off > 0; off >>= 1) {
    sum_g += __shfl_down(sum_g, off, 64);
    cnt += __shfl_down(cnt, off, 64);
  }
  __shared__ float ls[NWAVES], lc[NWAVES];
  const int lane = threadIdx.x & 63, wid = threadIdx.x >> 6;
  if (lane == 0) { ls[wid] = sum_g; lc[wid] = cnt; }
  __syncthreads();
  if (threadIdx.x == 0) {
    float S = ls[0], C = lc[0];
    for (int w2 = 1; w2 < NWAVES; ++w2) { S += ls[w2]; C += lc[w2]; }
    partials[blockIdx.x] = S;
    partials[NB + blockIdx.x] = C;
  }
}

// Kernel B: one block reduces the NB partial pairs and writes the scalar output.
__global__ __launch_bounds__(BS) void finalize_kernel(
    const float* __restrict__ partials, float* __restrict__ out) {
  float S = 0.f, C = 0.f;
  for (int i = threadIdx.x; i < NB; i += BS) {
    S += partials[i];
    C += partials[NB + i];
  }
  for (int off = 32; off > 0; off >>= 1) {
    S += __shfl_down(S, off, 64);
    C += __shfl_down(C, off, 64);
  }
  __shared__ float ls[NWAVES], lc[NWAVES];
  const int lane = threadIdx.x & 63, wid = threadIdx.x >> 6;
  if (lane == 0) { ls[wid] = S; lc[wid] = C; }
  __syncthreads();
  if (threadIdx.x == 0) {
    float St = ls[0], Ct = lc[0];
    for (int w = 1; w < NWAVES; ++w) { St += ls[w]; Ct += lc[w]; }
    const float K = 0.09973557010f;  // 1/(4*sqrt(2*pi))
    const float eps = 1e-6f;
    out[0] = 1.0f / fmaf(St, K, eps) + 1.0f / (Ct + eps);
  }
}

extern "C" void kernel_launch(void* const* d_in, const int* in_sizes, int n_in,
                              void* d_out, int out_size, void* d_ws, size_t ws_size,
                              hipStream_t stream) {
  const float* pts = (const float*)d_in[0];
  const float* cam = (const float*)d_in[1];
  float* out = (float*)d_out;
  float* partials = (float*)d_ws;  // 2*NB floats = 8 KB
  const int n_points = in_sizes[0] / 2;

  reduce_kernel<<<NB, BS, 0, stream>>>(pts, cam, partials, n_points);
  finalize_kernel<<<1, BS, 0, stream>>>(partials, out);
}